// Round 14
// baseline (401.233 us; speedup 1.0000x reference)
//
#include <hip/hip_runtime.h>
#include <math.h>
#include <stdint.h>

#define SEQ 4096
#define DIM 1024
#define NB  4
#define NTILE 32              // 4096/128 M-tiles per batch (128-packing of P)
#define TRI  528              // NTILE*(NTILE+1)/2 packed causal tiles

typedef __attribute__((ext_vector_type(8))) __bf16 bf16x8;
typedef __attribute__((ext_vector_type(4))) float  f32x4;
typedef __attribute__((ext_vector_type(4))) float  floatx4;
typedef __attribute__((ext_vector_type(8))) unsigned short ushortx8;
typedef __attribute__((ext_vector_type(4))) unsigned short ushortx4;

__device__ __forceinline__ unsigned short f2bf(float f){
  union { float f; unsigned int u; } c; c.f = f;
  unsigned int u = c.u;
  return (unsigned short)((u + 0x7fffu + ((u >> 16) & 1u)) >> 16);
}

__device__ __forceinline__ f32x4 mfma16(bf16x8 a, bf16x8 b, f32x4 c){
  return __builtin_amdgcn_mfma_f32_16x16x32_bf16(a, b, c, 0, 0, 0);
}

__device__ __forceinline__ void g2l16(void* lds, const void* g){
  __builtin_amdgcn_global_load_lds(
      (const __attribute__((address_space(1))) unsigned int*)g,
      (__attribute__((address_space(3))) unsigned int*)lds, 16, 0, 0);
}

#define WAITVM0 asm volatile("s_waitcnt vmcnt(0)" ::: "memory")

// raw barrier (no compiler-inserted vmcnt(0) drain)
#define BARRAW() do { asm volatile("" ::: "memory"); \
  __builtin_amdgcn_s_barrier(); asm volatile("" ::: "memory"); } while (0)
// counted vmcnt BEFORE the boundary barrier: publishes all-but-3 half-tiles
#define VM6_BAR() do { asm volatile("s_waitcnt vmcnt(6)" ::: "memory"); \
  __builtin_amdgcn_s_barrier(); asm volatile("" ::: "memory"); } while (0)
#define LGKM0() do { asm volatile("s_waitcnt lgkmcnt(0)" ::: "memory"); \
  __builtin_amdgcn_sched_barrier(0); } while (0)

// r11/r13-proven swizzle for 128B rows (pv kernel)
#define SWZB(r) (((r) & 7) << 4)

// ================= 8-phase 256x256 GEMM core (m201 template port) =========
// 512 thr (8 waves: wm=w>>2, wn=w&3). BK=64 split in 2 K-halves (kh).
// LDS buf (64KB): A.kh0 @0, A.kh1 @16384, B.kh0 @32768, B.kh1 @49152; x2 dbuf.
// Pack-pair lines: line L (128B) holds rows {2L,2L+1}, slot c=(r&1)*4+quad,
// stored at c^(L&7) -> conflict-free ds_read_b128 (r12-measured ~0).
// Per phase: read frags, stage 1 half-tile (2 g2l16), BAR, lgkm0, 16 MFMA, BAR.
// Stages: q0->(U+1).A.kh1, q1->(U+1).B.kh1 (other buffer);
//         q2->(U+2).A.kh0, q3->(U+2).B.kh0 (own buffer's DEAD kh0 regions).
// vmcnt(6) before the boundary barrier at q1-end and q3-end. Last tile peeled.

#define HT_STAGE(DST, SRC, KT, KH) do {                                   \
  g2l16((DST) + (size_t)t * 16,         (SRC) + so0 + (KT)*128 + (KH)*64);\
  g2l16((DST) + (size_t)(512 + t) * 16, (SRC) + so1 + (KT)*128 + (KH)*64);\
} while (0)

#define MFMA16X(NH) do {                                                  \
  __builtin_amdgcn_s_setprio(1);                                          \
  _Pragma("unroll")                                                       \
  for (int i = 0; i < 8; ++i){                                            \
    acc[i][(NH)*2]     = mfma16(af[i], b0, acc[i][(NH)*2]);               \
    acc[i][(NH)*2 + 1] = mfma16(af[i], b1, acc[i][(NH)*2 + 1]);           \
  }                                                                       \
  __builtin_amdgcn_s_setprio(0);                                          \
} while (0)

#define CORE8PH(ASRC, BSRC)                                               \
  f32x4 acc[8][4];                                                        \
  _Pragma("unroll")                                                       \
  for (int i = 0; i < 8; ++i)                                             \
    _Pragma("unroll")                                                     \
    for (int j = 0; j < 4; ++j) acc[i][j] = (f32x4)0.0f;                  \
  int aoff[8], boff[4];                                                   \
  _Pragma("unroll")                                                       \
  for (int i = 0; i < 8; ++i){                                            \
    int rr = wm*128 + i*16 + lr;                                          \
    aoff[i] = (rr>>1)*128 + ((((rr&1)*4 + lk) ^ ((rr>>1)&7))*16);         \
  }                                                                       \
  _Pragma("unroll")                                                       \
  for (int j = 0; j < 4; ++j){                                            \
    int rr = wn*64 + j*16 + lr;                                           \
    boff[j] = 32768 + (rr>>1)*128 + ((((rr&1)*4 + lk) ^ ((rr>>1)&7))*16); \
  }                                                                       \
  int so0, so1;                                                           \
  {                                                                       \
    int L0 = t >> 3,        sx0 = (t & 7) ^ (L0 & 7);                     \
    so0 = (2*L0 + (sx0>>2))*2048 + (sx0&3)*16;                            \
    int L1 = (512+t) >> 3,  sx1 = ((512+t) & 7) ^ (L1 & 7);               \
    so1 = (2*L1 + (sx1>>2))*2048 + (sx1&3)*16;                            \
  }                                                                       \
  /* prologue: 6 half-tiles in stream order */                            \
  HT_STAGE(ldsb,          ASRC, 0, 0);                                    \
  HT_STAGE(ldsb + 32768,  BSRC, 0, 0);                                    \
  HT_STAGE(ldsb + 16384,  ASRC, 0, 1);                                    \
  HT_STAGE(ldsb + 49152,  BSRC, 0, 1);                                    \
  HT_STAGE(ldsb + 65536,  ASRC, 1, 0);                                    \
  HT_STAGE(ldsb + 98304,  BSRC, 1, 0);                                    \
  asm volatile("s_waitcnt vmcnt(8)" ::: "memory");                        \
  __builtin_amdgcn_s_barrier();                                           \
  asm volatile("" ::: "memory");                                          \
  for (int U = 0; U < 15; ++U){                                           \
    char* bufc = ldsb + (size_t)(U & 1) * 65536;                          \
    char* bufn = ldsb + (size_t)((U + 1) & 1) * 65536;                    \
    bf16x8 af[8], b0, b1;                                                 \
    /* q0: ks=0 nh=0 */                                                   \
    _Pragma("unroll")                                                     \
    for (int i = 0; i < 8; ++i) af[i] = *(const bf16x8*)(bufc + aoff[i]); \
    b0 = *(const bf16x8*)(bufc + boff[0]);                                \
    b1 = *(const bf16x8*)(bufc + boff[1]);                                \
    HT_STAGE(bufn + 16384, ASRC, U + 1, 1);                               \
    BARRAW(); LGKM0();                                                    \
    MFMA16X(0);                                                           \
    BARRAW();                                                             \
    /* q1: ks=0 nh=1 (af reused) */                                       \
    b0 = *(const bf16x8*)(bufc + boff[2]);                                \
    b1 = *(const bf16x8*)(bufc + boff[3]);                                \
    HT_STAGE(bufn + 49152, BSRC, U + 1, 1);                               \
    BARRAW(); LGKM0();                                                    \
    MFMA16X(1);                                                           \
    VM6_BAR();                                                            \
    /* q2: ks=1 nh=0 */                                                   \
    _Pragma("unroll")                                                     \
    for (int i = 0; i < 8; ++i)                                           \
      af[i] = *(const bf16x8*)(bufc + 16384 + aoff[i]);                   \
    b0 = *(const bf16x8*)(bufc + boff[0] + 16384);                        \
    b1 = *(const bf16x8*)(bufc + boff[1] + 16384);                        \
    if (U < 14) HT_STAGE(bufc, ASRC, U + 2, 0);                           \
    BARRAW(); LGKM0();                                                    \
    MFMA16X(0);                                                           \
    BARRAW();                                                             \
    /* q3: ks=1 nh=1 */                                                   \
    b0 = *(const bf16x8*)(bufc + boff[2] + 16384);                        \
    b1 = *(const bf16x8*)(bufc + boff[3] + 16384);                        \
    if (U < 14) HT_STAGE(bufc + 32768, BSRC, U + 2, 0);                   \
    BARRAW(); LGKM0();                                                    \
    MFMA16X(1);                                                           \
    VM6_BAR();                                                            \
  }                                                                       \
  /* peeled last tile (U=15, buf1): drain once, plain compute */          \
  {                                                                       \
    char* bufc = ldsb + 65536;                                            \
    WAITVM0;                                                              \
    __builtin_amdgcn_s_barrier();                                         \
    asm volatile("" ::: "memory");                                        \
    _Pragma("unroll")                                                     \
    for (int ks = 0; ks < 2; ++ks){                                       \
      bf16x8 af[8], b0, b1;                                               \
      _Pragma("unroll")                                                   \
      for (int i = 0; i < 8; ++i)                                         \
        af[i] = *(const bf16x8*)(bufc + ks*16384 + aoff[i]);              \
      _Pragma("unroll")                                                   \
      for (int j = 0; j < 4; j += 2){                                     \
        b0 = *(const bf16x8*)(bufc + boff[j]   + ks*16384);               \
        b1 = *(const bf16x8*)(bufc + boff[j+1] + ks*16384);               \
        _Pragma("unroll")                                                 \
        for (int i = 0; i < 8; ++i){                                      \
          acc[i][j]   = mfma16(af[i], b0, acc[i][j]);                     \
          acc[i][j+1] = mfma16(af[i], b1, acc[i][j+1]);                   \
        }                                                                 \
      }                                                                   \
    }                                                                     \
  }

// ---------------- fp32 -> bf16 conversion ----------------
__global__ void cvt_kernel(const float* __restrict__ src,
                           unsigned short* __restrict__ dst, int n4){
  int i = blockIdx.x * blockDim.x + threadIdx.x;
  if (i >= n4) return;
  floatx4 v = *((const floatx4*)src + i);
  ushortx4 o;
  o[0] = f2bf(v[0]); o[1] = f2bf(v[1]); o[2] = f2bf(v[2]); o[3] = f2bf(v[3]);
  *((ushortx4*)dst + i) = o;
}

// ---------------- QKV projection GEMM: 256^2 8-phase + XCD remap ----------
__global__ __launch_bounds__(512, 1) void gemm_qkv(
    const unsigned short* __restrict__ E,
    const unsigned short* __restrict__ W3,
    unsigned short* __restrict__ Qd,
    unsigned short* __restrict__ Kd,
    unsigned short* __restrict__ Vd)
{
  __shared__ char ldsbuf[131072];
  char* ldsb = ldsbuf;

  // colocate the 12 blocks (4 n x 3 z) sharing one 256-row E-slab per XCD
  const int bid = blockIdx.x;          // 0..767
  const int xcd = bid & 7;
  const int s   = bid >> 3;            // 0..95
  const int ml  = s / 12;
  const int r12 = s - ml * 12;
  const int mt  = xcd * 8 + ml;        // 0..63
  const int nt  = r12 & 3;             // 0..3
  const int z   = r12 >> 2;            // 0..2

  const int m0 = mt * 256;
  const int n0 = nt * 256;
  const unsigned short* W = W3 + (size_t)z * (DIM * (size_t)DIM);
  unsigned short* dst = z == 0 ? Qd : (z == 1 ? Kd : Vd);

  const int t  = threadIdx.x;
  const int w  = t >> 6;
  const int l  = t & 63;
  const int lr = l & 15;
  const int lk = l >> 4;
  const int wm = w >> 2;
  const int wn = w & 3;

  const char* Asl = (const char*)E + (size_t)m0 * 2048;
  const char* Bsl = (const char*)W + (size_t)n0 * 2048;

  CORE8PH(Asl, Bsl);

  #pragma unroll
  for (int i = 0; i < 8; ++i)
    #pragma unroll
    for (int j = 0; j < 4; ++j)
      #pragma unroll
      for (int r = 0; r < 4; ++r){
        int row = wm * 128 + i * 16 + lk * 4 + r;
        int col = wn * 64 + j * 16 + lr;
        dst[(size_t)(m0 + row) * DIM + n0 + col] = f2bf(acc[i][j][r]);
      }
}

// ---------------- V transpose ----------------
__global__ __launch_bounds__(256) void transpose_v(
    const unsigned short* __restrict__ V, unsigned short* __restrict__ VT)
{
  __shared__ unsigned short T[64][72];
  const int b  = blockIdx.z;
  const int s0 = blockIdx.x * 64;
  const int a0 = blockIdx.y * 64;
  const unsigned short* Vb = V + (size_t)b * SEQ * DIM;
  unsigned short* VTb = VT + (size_t)b * DIM * SEQ;
  const int t = threadIdx.x;
  const int r = t >> 3, cg = t & 7;
  #pragma unroll
  for (int p = 0; p < 2; ++p){
    int row = r + p * 32;
    ushortx8 v = *(const ushortx8*)(Vb + (size_t)(s0 + row) * DIM + a0 + cg*8);
    *(ushortx8*)&T[row][cg*8] = v;
  }
  __syncthreads();
  #pragma unroll
  for (int p = 0; p < 2; ++p){
    int ar = r + p * 32;
    ushortx8 o;
    #pragma unroll
    for (int j = 0; j < 8; ++j) o[j] = T[cg*8 + j][ar];
    *(ushortx8*)(VTb + (size_t)(a0 + ar) * SEQ + s0 + cg*8) = o;
  }
}

// ---------------- S/P GEMM: 256^2 8-phase, P = exp(scale*QK^T) causal -----
__global__ __launch_bounds__(512, 1) void sp_gemm(
    const unsigned short* __restrict__ Q,
    const unsigned short* __restrict__ K,
    unsigned short* __restrict__ Sp,
    float* __restrict__ lrow)
{
  const int TJ = blockIdx.x;
  const int TI = blockIdx.y;
  if (TJ > TI) return;
  const int b  = blockIdx.z;

  __shared__ char ldsbuf[131072];
  char* ldsb = ldsbuf;

  const int m0 = TI * 256;
  const int n0 = TJ * 256;

  const int t  = threadIdx.x;
  const int w  = t >> 6;
  const int l  = t & 63;
  const int lr = l & 15;
  const int lk = l >> 4;
  const int wm = w >> 2;
  const int wn = w & 3;

  const char* Asl = (const char*)(Q + (size_t)b * SEQ * DIM) + (size_t)m0 * 2048;
  const char* Bsl = (const char*)(K + (size_t)b * SEQ * DIM) + (size_t)n0 * 2048;

  CORE8PH(Asl, Bsl);

  // epilogue (r12-verified): P = exp(scale*acc) masked; packed 128-subtiles
  const float scale = 0.03125f;  // 1/sqrt(1024)
  const unsigned short* SpB = Sp + (size_t)b * TRI * 16384;
  float* lb = lrow + (size_t)b * SEQ;

  unsigned short* stile[2][2];
  #pragma unroll
  for (int h = 0; h < 2; ++h)
    #pragma unroll
    for (int cb = 0; cb < 2; ++cb){
      int ti128 = 2 * TI + h;
      int tj128 = 2 * TJ + cb;
      stile[h][cb] = (tj128 <= ti128)
        ? (unsigned short*)SpB + (size_t)(ti128 * (ti128 + 1) / 2 + tj128) * 16384
        : (unsigned short*)0;
    }

  #pragma unroll
  for (int i = 0; i < 8; ++i){
    float rs[4] = {0.f, 0.f, 0.f, 0.f};
    const int rowq = wm * 128 + i * 16;           // +lk*4+r
    #pragma unroll
    for (int j = 0; j < 4; ++j){
      const int col = wn * 64 + j * 16 + lr;
      unsigned short* st = stile[rowq >> 7][col >> 7];
      #pragma unroll
      for (int r = 0; r < 4; ++r){
        int row = rowq + lk * 4 + r;
        float p = 0.0f;
        if (n0 + col <= m0 + row) p = __expf(acc[i][j][r] * scale);
        rs[r] += p;
        if (st) st[(row & 127) * 128 + (col & 127)] = f2bf(p);
      }
    }
    #pragma unroll
    for (int r = 0; r < 4; ++r){
      float v = rs[r];
      v += __shfl_xor(v, 1, 64);
      v += __shfl_xor(v, 2, 64);
      v += __shfl_xor(v, 4, 64);
      v += __shfl_xor(v, 8, 64);
      if (lr == 0)
        atomicAdd(&lb[m0 + rowq + lk * 4 + r], v);
    }
  }
}

// ---------------- PV GEMM: O = (P V) / l (r13 form, unchanged) ------------
__global__ __launch_bounds__(256, 2) void pv_gemm(
    const unsigned short* __restrict__ Sp,
    const unsigned short* __restrict__ VT,
    const float* __restrict__ lrow,
    float* __restrict__ out)
{
  __shared__ unsigned short As[128 * 64];
  __shared__ unsigned short Bs[128 * 64];

  const int nx = blockIdx.x;
  const int pr = blockIdx.y;
  const int b  = blockIdx.z;
  const int t  = threadIdx.x;

  const int l  = t & 63;
  const int w  = t >> 6;
  const int lr = l & 15;
  const int lk = l >> 4;
  const int lk16 = lk * 16;
  const int wr = (w >> 1) * 64;
  const int wc = (w & 1) * 64;

  const int n0 = nx * 128;
  const char* VTb = (const char*)(VT + (size_t)b * DIM * SEQ) + (size_t)n0 * 8192;
  const unsigned short* Spb = Sp + (size_t)b * TRI * 16384;

  for (int half = 0; half < 2; ++half){
    const int ti = half ? pr : (31 - pr);
    const int m0 = ti * 128;
    const char* Pt = (const char*)(Spb + (size_t)(ti * (ti + 1) / 2) * 16384);
    const int ksteps = 2 * (ti + 1);

    f32x4 acc[4][4];
    #pragma unroll
    for (int i = 0; i < 4; ++i)
      #pragma unroll
      for (int j = 0; j < 4; ++j) acc[i][j] = (f32x4)0.0f;

    for (int s = 0; s < ksteps; ++s){
      #pragma unroll
      for (int _c = 0; _c < 4; ++_c){
        int _id  = _c * 256 + t;
        int _row = _id >> 3;
        int _sw  = ((_id & 7) * 16) ^ SWZB(_row);
        g2l16((char*)As + (size_t)_id * 16,
              Pt + (size_t)(s >> 1) * 32768 + (size_t)_row * 256 + (s & 1) * 128 + _sw);
        g2l16((char*)Bs + (size_t)_id * 16,
              VTb + (size_t)_row * 8192 + s * 128 + _sw);
      }
      WAITVM0;
      __syncthreads();
      #pragma unroll
      for (int _ks = 0; _ks < 2; ++_ks){
        bf16x8 _af[4], _bf[4];
        #pragma unroll
        for (int _i = 0; _i < 4; ++_i){
          int _ra = wr + _i*16 + lr;
          int _rb = wc + _i*16 + lr;
          _af[_i] = *(const bf16x8*)((const char*)As + (size_t)_ra * 128
                                     + ((_ks*64 + lk16) ^ SWZB(_ra)));
          _bf[_i] = *(const bf16x8*)((const char*)Bs + (size_t)_rb * 128
                                     + ((_ks*64 + lk16) ^ SWZB(_rb)));
        }
        #pragma unroll
        for (int _i = 0; _i < 4; ++_i)
          #pragma unroll
          for (int _j = 0; _j < 4; ++_j)
            acc[_i][_j] = mfma16(_af[_i], _bf[_j], acc[_i][_j]);
      }
      __syncthreads();
    }

    const float* lb = lrow + (size_t)b * SEQ + m0;
    float* ob = out + ((size_t)b * SEQ + m0) * DIM + n0;
    #pragma unroll
    for (int i = 0; i < 4; ++i)
      #pragma unroll
      for (int r = 0; r < 4; ++r){
        int row = wr + i*16 + lk*4 + r;
        float inv = 1.0f / lb[row];
        #pragma unroll
        for (int j = 0; j < 4; ++j)
          ob[(size_t)row * DIM + wc + j*16 + lr] = acc[i][j][r] * inv;
      }
  }
}

// ---------------- launch ----------------
extern "C" void kernel_launch(void* const* d_in, const int* in_sizes, int n_in,
                              void* d_out, int out_size, void* d_ws, size_t ws_size,
                              hipStream_t stream)
{
  (void)in_sizes; (void)n_in; (void)out_size; (void)ws_size;
  const float* emb = (const float*)d_in[0];
  const float* Wq  = (const float*)d_in[1];
  const float* Wk  = (const float*)d_in[2];
  const float* Wv  = (const float*)d_in[3];

  char* ws = (char*)d_ws;
  unsigned short* EB = (unsigned short*)ws;                    // 32MB (reused as VT)
  unsigned short* WB = (unsigned short*)(ws + 33554432);       // 6MB: Wq|Wk|Wv bf16
  unsigned short* Qb = (unsigned short*)(ws + 39845888);       // 32MB
  unsigned short* Kb = (unsigned short*)(ws + 73400320);       // 32MB
  unsigned short* Sp = (unsigned short*)(ws + 106954752);      // 66MB packed P tiles
  float*          lr = (float*)(ws + 176160768);               // 64KB row sums
  unsigned short* Vb = (unsigned short*)d_out;                 // V scratch in out buffer
  unsigned short* VT = EB;                                     // alias: E dead after gemm

  hipMemsetAsync(lr, 0, (size_t)NB * SEQ * sizeof(float), stream);

  cvt_kernel<<<16384, 256, 0, stream>>>(emb, EB, 4194304);
  cvt_kernel<<<1024, 256, 0, stream>>>(Wq, WB,           262144);
  cvt_kernel<<<1024, 256, 0, stream>>>(Wk, WB + 1048576, 262144);
  cvt_kernel<<<1024, 256, 0, stream>>>(Wv, WB + 2097152, 262144);

  gemm_qkv<<<768, 512, 0, stream>>>(EB, WB, Qb, Kb, Vb);
  transpose_v<<<dim3(64, 16, 4), 256, 0, stream>>>(Vb, VT);

  sp_gemm<<<dim3(16, 16, 4), 512, 0, stream>>>(Qb, Kb, Sp, lr);
  pv_gemm<<<dim3(8, 16, 4), 256, 0, stream>>>(Sp, VT, lr, (float*)d_out);
}

// Round 15
// 323.856 us; speedup vs baseline: 1.2389x; 1.2389x over previous
//
#include <hip/hip_runtime.h>
#include <math.h>
#include <stdint.h>

#define SEQ 4096
#define DIM 1024
#define NB  4
#define NTILE 32              // 4096/128 M-tiles per batch (128-packing of P)
#define TRI  528              // NTILE*(NTILE+1)/2 packed causal tiles

typedef __attribute__((ext_vector_type(8))) __bf16 bf16x8;
typedef __attribute__((ext_vector_type(4))) float  f32x4;
typedef __attribute__((ext_vector_type(4))) float  floatx4;
typedef __attribute__((ext_vector_type(8))) unsigned short ushortx8;
typedef __attribute__((ext_vector_type(4))) unsigned short ushortx4;

__device__ __forceinline__ unsigned short f2bf(float f){
  union { float f; unsigned int u; } c; c.f = f;
  unsigned int u = c.u;
  return (unsigned short)((u + 0x7fffu + ((u >> 16) & 1u)) >> 16);
}

__device__ __forceinline__ f32x4 mfma16(bf16x8 a, bf16x8 b, f32x4 c){
  return __builtin_amdgcn_mfma_f32_16x16x32_bf16(a, b, c, 0, 0, 0);
}

__device__ __forceinline__ void g2l16(void* lds, const void* g){
  __builtin_amdgcn_global_load_lds(
      (const __attribute__((address_space(1))) unsigned int*)g,
      (__attribute__((address_space(3))) unsigned int*)lds, 16, 0, 0);
}

#define WAITVM0 asm volatile("s_waitcnt vmcnt(0)" ::: "memory")

// raw barrier / counted-vmcnt barriers (qkv 8-phase core)
#define BARRAW() do { asm volatile("" ::: "memory"); \
  __builtin_amdgcn_s_barrier(); asm volatile("" ::: "memory"); } while (0)
#define VM6_BAR() do { asm volatile("s_waitcnt vmcnt(6)" ::: "memory"); \
  __builtin_amdgcn_s_barrier(); asm volatile("" ::: "memory"); } while (0)
#define LGKM0() do { asm volatile("s_waitcnt lgkmcnt(0)" ::: "memory"); \
  __builtin_amdgcn_sched_barrier(0); } while (0)

// r11/r13-proven swizzle for 128B rows (sp/pv kernels)
#define SWZB(r) (((r) & 7) << 4)

// stage one 128x64 bf16 tile (linear LDS dest, pre-swizzled global source)
#define STAGE_AB(Aptr, Astr, Bptr, Bstr) do { \
  _Pragma("unroll") \
  for (int _c = 0; _c < 4; ++_c){ \
    int _id  = _c * 256 + t; \
    int _row = _id >> 3; \
    int _sw  = ((_id & 7) * 16) ^ SWZB(_row); \
    g2l16((char*)As + (size_t)_id * 16, \
          (const char*)(Aptr) + (size_t)_row * (Astr) + _sw); \
    g2l16((char*)Bs + (size_t)_id * 16, \
          (const char*)(Bptr) + (size_t)_row * (Bstr) + _sw); \
  } \
} while (0)

// 128x128-tile MFMA step over one staged 64-K slab (swizzled ds_reads)
#define COMPUTE128S() do { \
  _Pragma("unroll") \
  for (int _ks = 0; _ks < 2; ++_ks){ \
    bf16x8 _af[4], _bf[4]; \
    _Pragma("unroll") \
    for (int _i = 0; _i < 4; ++_i){ \
      int _ra = wr + _i*16 + lr; \
      int _rb = wc + _i*16 + lr; \
      _af[_i] = *(const bf16x8*)((const char*)As + (size_t)_ra * 128 \
                                 + ((_ks*64 + lk16) ^ SWZB(_ra))); \
      _bf[_i] = *(const bf16x8*)((const char*)Bs + (size_t)_rb * 128 \
                                 + ((_ks*64 + lk16) ^ SWZB(_rb))); \
    } \
    __builtin_amdgcn_s_setprio(1); \
    _Pragma("unroll") \
    for (int _i = 0; _i < 4; ++_i) \
      _Pragma("unroll") \
      for (int _j = 0; _j < 4; ++_j) \
        acc[_i][_j] = mfma16(_af[_i], _bf[_j], acc[_i][_j]); \
    __builtin_amdgcn_s_setprio(0); \
  } \
} while (0)

// ================= 8-phase 256x256 GEMM core (qkv only; r14-measured) =====
#define HT_STAGE(DST, SRC, KT, KH) do {                                   \
  g2l16((DST) + (size_t)t * 16,         (SRC) + so0 + (KT)*128 + (KH)*64);\
  g2l16((DST) + (size_t)(512 + t) * 16, (SRC) + so1 + (KT)*128 + (KH)*64);\
} while (0)

#define MFMA16X(NH) do {                                                  \
  __builtin_amdgcn_s_setprio(1);                                          \
  _Pragma("unroll")                                                       \
  for (int i = 0; i < 8; ++i){                                            \
    acc[i][(NH)*2]     = mfma16(af[i], b0, acc[i][(NH)*2]);               \
    acc[i][(NH)*2 + 1] = mfma16(af[i], b1, acc[i][(NH)*2 + 1]);           \
  }                                                                       \
  __builtin_amdgcn_s_setprio(0);                                          \
} while (0)

#define CORE8PH(ASRC, BSRC)                                               \
  f32x4 acc[8][4];                                                        \
  _Pragma("unroll")                                                       \
  for (int i = 0; i < 8; ++i)                                             \
    _Pragma("unroll")                                                     \
    for (int j = 0; j < 4; ++j) acc[i][j] = (f32x4)0.0f;                  \
  int aoff[8], boff[4];                                                   \
  _Pragma("unroll")                                                       \
  for (int i = 0; i < 8; ++i){                                            \
    int rr = wm*128 + i*16 + lr;                                          \
    aoff[i] = (rr>>1)*128 + ((((rr&1)*4 + lk) ^ ((rr>>1)&7))*16);         \
  }                                                                       \
  _Pragma("unroll")                                                       \
  for (int j = 0; j < 4; ++j){                                            \
    int rr = wn*64 + j*16 + lr;                                           \
    boff[j] = 32768 + (rr>>1)*128 + ((((rr&1)*4 + lk) ^ ((rr>>1)&7))*16); \
  }                                                                       \
  int so0, so1;                                                           \
  {                                                                       \
    int L0 = t >> 3,        sx0 = (t & 7) ^ (L0 & 7);                     \
    so0 = (2*L0 + (sx0>>2))*2048 + (sx0&3)*16;                            \
    int L1 = (512+t) >> 3,  sx1 = ((512+t) & 7) ^ (L1 & 7);               \
    so1 = (2*L1 + (sx1>>2))*2048 + (sx1&3)*16;                            \
  }                                                                       \
  HT_STAGE(ldsb,          ASRC, 0, 0);                                    \
  HT_STAGE(ldsb + 32768,  BSRC, 0, 0);                                    \
  HT_STAGE(ldsb + 16384,  ASRC, 0, 1);                                    \
  HT_STAGE(ldsb + 49152,  BSRC, 0, 1);                                    \
  HT_STAGE(ldsb + 65536,  ASRC, 1, 0);                                    \
  HT_STAGE(ldsb + 98304,  BSRC, 1, 0);                                    \
  asm volatile("s_waitcnt vmcnt(8)" ::: "memory");                        \
  __builtin_amdgcn_s_barrier();                                           \
  asm volatile("" ::: "memory");                                          \
  for (int U = 0; U < 15; ++U){                                           \
    char* bufc = ldsb + (size_t)(U & 1) * 65536;                          \
    char* bufn = ldsb + (size_t)((U + 1) & 1) * 65536;                    \
    bf16x8 af[8], b0, b1;                                                 \
    _Pragma("unroll")                                                     \
    for (int i = 0; i < 8; ++i) af[i] = *(const bf16x8*)(bufc + aoff[i]); \
    b0 = *(const bf16x8*)(bufc + boff[0]);                                \
    b1 = *(const bf16x8*)(bufc + boff[1]);                                \
    HT_STAGE(bufn + 16384, ASRC, U + 1, 1);                               \
    BARRAW(); LGKM0();                                                    \
    MFMA16X(0);                                                           \
    BARRAW();                                                             \
    b0 = *(const bf16x8*)(bufc + boff[2]);                                \
    b1 = *(const bf16x8*)(bufc + boff[3]);                                \
    HT_STAGE(bufn + 49152, BSRC, U + 1, 1);                               \
    BARRAW(); LGKM0();                                                    \
    MFMA16X(1);                                                           \
    VM6_BAR();                                                            \
    _Pragma("unroll")                                                     \
    for (int i = 0; i < 8; ++i)                                           \
      af[i] = *(const bf16x8*)(bufc + 16384 + aoff[i]);                   \
    b0 = *(const bf16x8*)(bufc + boff[0] + 16384);                        \
    b1 = *(const bf16x8*)(bufc + boff[1] + 16384);                        \
    if (U < 14) HT_STAGE(bufc, ASRC, U + 2, 0);                           \
    BARRAW(); LGKM0();                                                    \
    MFMA16X(0);                                                           \
    BARRAW();                                                             \
    b0 = *(const bf16x8*)(bufc + boff[2] + 16384);                        \
    b1 = *(const bf16x8*)(bufc + boff[3] + 16384);                        \
    if (U < 14) HT_STAGE(bufc + 32768, BSRC, U + 2, 0);                   \
    BARRAW(); LGKM0();                                                    \
    MFMA16X(1);                                                           \
    VM6_BAR();                                                            \
  }                                                                       \
  {                                                                       \
    char* bufc = ldsb + 65536;                                            \
    WAITVM0;                                                              \
    __builtin_amdgcn_s_barrier();                                         \
    asm volatile("" ::: "memory");                                        \
    _Pragma("unroll")                                                     \
    for (int ks = 0; ks < 2; ++ks){                                       \
      bf16x8 af[8], b0, b1;                                               \
      _Pragma("unroll")                                                   \
      for (int i = 0; i < 8; ++i)                                         \
        af[i] = *(const bf16x8*)(bufc + ks*16384 + aoff[i]);              \
      _Pragma("unroll")                                                   \
      for (int j = 0; j < 4; j += 2){                                     \
        b0 = *(const bf16x8*)(bufc + boff[j]   + ks*16384);               \
        b1 = *(const bf16x8*)(bufc + boff[j+1] + ks*16384);               \
        _Pragma("unroll")                                                 \
        for (int i = 0; i < 8; ++i){                                      \
          acc[i][j]   = mfma16(af[i], b0, acc[i][j]);                     \
          acc[i][j+1] = mfma16(af[i], b1, acc[i][j+1]);                   \
        }                                                                 \
      }                                                                   \
    }                                                                     \
  }

// ---------------- fp32 -> bf16 conversion ----------------
__global__ void cvt_kernel(const float* __restrict__ src,
                           unsigned short* __restrict__ dst, int n4){
  int i = blockIdx.x * blockDim.x + threadIdx.x;
  if (i >= n4) return;
  floatx4 v = *((const floatx4*)src + i);
  ushortx4 o;
  o[0] = f2bf(v[0]); o[1] = f2bf(v[1]); o[2] = f2bf(v[2]); o[3] = f2bf(v[3]);
  *((ushortx4*)dst + i) = o;
}

// ---------------- QKV projection GEMM: 256^2 8-phase + XCD remap (r14) ----
__global__ __launch_bounds__(512, 1) void gemm_qkv(
    const unsigned short* __restrict__ E,
    const unsigned short* __restrict__ W3,
    unsigned short* __restrict__ Qd,
    unsigned short* __restrict__ Kd,
    unsigned short* __restrict__ Vd)
{
  __shared__ char ldsbuf[131072];
  char* ldsb = ldsbuf;

  const int bid = blockIdx.x;          // 0..767
  const int xcd = bid & 7;
  const int s   = bid >> 3;            // 0..95
  const int ml  = s / 12;
  const int r12 = s - ml * 12;
  const int mt  = xcd * 8 + ml;        // 0..63
  const int nt  = r12 & 3;             // 0..3
  const int z   = r12 >> 2;            // 0..2

  const int m0 = mt * 256;
  const int n0 = nt * 256;
  const unsigned short* W = W3 + (size_t)z * (DIM * (size_t)DIM);
  unsigned short* dst = z == 0 ? Qd : (z == 1 ? Kd : Vd);

  const int t  = threadIdx.x;
  const int w  = t >> 6;
  const int l  = t & 63;
  const int lr = l & 15;
  const int lk = l >> 4;
  const int wm = w >> 2;
  const int wn = w & 3;

  const char* Asl = (const char*)E + (size_t)m0 * 2048;
  const char* Bsl = (const char*)W + (size_t)n0 * 2048;

  CORE8PH(Asl, Bsl);

  #pragma unroll
  for (int i = 0; i < 8; ++i)
    #pragma unroll
    for (int j = 0; j < 4; ++j)
      #pragma unroll
      for (int r = 0; r < 4; ++r){
        int row = wm * 128 + i * 16 + lk * 4 + r;
        int col = wn * 64 + j * 16 + lr;
        dst[(size_t)(m0 + row) * DIM + n0 + col] = f2bf(acc[i][j][r]);
      }
}

// ---------------- V transpose ----------------
__global__ __launch_bounds__(256) void transpose_v(
    const unsigned short* __restrict__ V, unsigned short* __restrict__ VT)
{
  __shared__ unsigned short T[64][72];
  const int b  = blockIdx.z;
  const int s0 = blockIdx.x * 64;
  const int a0 = blockIdx.y * 64;
  const unsigned short* Vb = V + (size_t)b * SEQ * DIM;
  unsigned short* VTb = VT + (size_t)b * DIM * SEQ;
  const int t = threadIdx.x;
  const int r = t >> 3, cg = t & 7;
  #pragma unroll
  for (int p = 0; p < 2; ++p){
    int row = r + p * 32;
    ushortx8 v = *(const ushortx8*)(Vb + (size_t)(s0 + row) * DIM + a0 + cg*8);
    *(ushortx8*)&T[row][cg*8] = v;
  }
  __syncthreads();
  #pragma unroll
  for (int p = 0; p < 2; ++p){
    int ar = r + p * 32;
    ushortx8 o;
    #pragma unroll
    for (int j = 0; j < 8; ++j) o[j] = T[cg*8 + j][ar];
    *(ushortx8*)(VTb + (size_t)(a0 + ar) * SEQ + s0 + cg*8) = o;
  }
}

// ---------------- S/P GEMM: r13 128^2 form, triangular-packed XCD grid ----
// grid (528, NB). p chunked: xcd = orig&7 owns 66 consecutive triangular
// indices -> consecutive p share ti (Q-slab L2-resident per XCD).
__global__ __launch_bounds__(256, 2) void sp_gemm(
    const unsigned short* __restrict__ Q,
    const unsigned short* __restrict__ K,
    unsigned short* __restrict__ Sp,
    float* __restrict__ lrow)
{
  const int orig = blockIdx.x;         // 0..527
  const int p    = (orig & 7) * 66 + (orig >> 3);
  const int b    = blockIdx.y;

  int ti = (int)((__builtin_sqrtf(8.0f * (float)p + 1.0f) - 1.0f) * 0.5f);
  while ((ti + 1) * (ti + 2) / 2 <= p) ++ti;
  while (ti * (ti + 1) / 2 > p) --ti;
  const int tj = p - ti * (ti + 1) / 2;

  __shared__ unsigned short As[128 * 64];
  __shared__ unsigned short Bs[128 * 64];

  const int t  = threadIdx.x;
  const int m0 = ti * 128;
  const int n0 = tj * 128;

  const int l  = t & 63;
  const int w  = t >> 6;
  const int lr = l & 15;
  const int lk = l >> 4;
  const int lk16 = lk * 16;
  const int wr = (w >> 1) * 64;
  const int wc = (w & 1) * 64;

  const char* Abase = (const char*)(Q + (size_t)b * SEQ * DIM) + (size_t)m0 * 2048;
  const char* Bbase = (const char*)(K + (size_t)b * SEQ * DIM) + (size_t)n0 * 2048;

  f32x4 acc[4][4];
  #pragma unroll
  for (int i = 0; i < 4; ++i)
    #pragma unroll
    for (int j = 0; j < 4; ++j) acc[i][j] = (f32x4)0.0f;

  for (int kt = 0; kt < DIM / 64; ++kt){
    STAGE_AB(Abase + kt * 128, 2048, Bbase + kt * 128, 2048);
    WAITVM0;
    __syncthreads();
    COMPUTE128S();
    __syncthreads();
  }

  // epilogue: P = exp(scale*acc) masked; bf16 packed write; row-sum atomics
  const float scale = 0.03125f;  // 1/sqrt(1024)
  unsigned short* tile = Sp + ((size_t)b * TRI + (size_t)p) * 16384;
  float* lb = lrow + (size_t)b * SEQ + m0;

  #pragma unroll
  for (int i = 0; i < 4; ++i){
    float rs[4] = {0.f, 0.f, 0.f, 0.f};
    #pragma unroll
    for (int j = 0; j < 4; ++j){
      #pragma unroll
      for (int r = 0; r < 4; ++r){
        int row = wr + i*16 + lk*4 + r;
        int col = wc + j*16 + lr;
        float pv = 0.0f;
        if (n0 + col <= m0 + row) pv = __expf(acc[i][j][r] * scale);
        rs[r] += pv;
        tile[row * 128 + col] = f2bf(pv);
      }
    }
    #pragma unroll
    for (int r = 0; r < 4; ++r){
      float v = rs[r];
      v += __shfl_xor(v, 1, 64);
      v += __shfl_xor(v, 2, 64);
      v += __shfl_xor(v, 4, 64);
      v += __shfl_xor(v, 8, 64);
      if (lr == 0)
        atomicAdd(&lb[wr + i*16 + lk*4 + r], v);
    }
  }
}

// ---------------- PV GEMM: r13 body, XCD-chunked (same-pr colocated) ------
// grid (128, NB). f chunked: xcd = f&7 gets 16 consecutive work items
// g = (f&7)*16 + f>>3; pr = g>>3 (P rows shared by its 8 nx blocks), nx = g&7.
__global__ __launch_bounds__(256, 2) void pv_gemm(
    const unsigned short* __restrict__ Sp,
    const unsigned short* __restrict__ VT,
    const float* __restrict__ lrow,
    float* __restrict__ out)
{
  __shared__ unsigned short As[128 * 64];
  __shared__ unsigned short Bs[128 * 64];

  const int f  = blockIdx.x;           // 0..127
  const int g  = (f & 7) * 16 + (f >> 3);
  const int pr = g >> 3;               // 0..15
  const int nx = g & 7;                // 0..7
  const int b  = blockIdx.y;
  const int t  = threadIdx.x;

  const int l  = t & 63;
  const int w  = t >> 6;
  const int lr = l & 15;
  const int lk = l >> 4;
  const int lk16 = lk * 16;
  const int wr = (w >> 1) * 64;
  const int wc = (w & 1) * 64;

  const int n0 = nx * 128;
  const char* VTb = (const char*)(VT + (size_t)b * DIM * SEQ) + (size_t)n0 * 8192;
  const unsigned short* Spb = Sp + (size_t)b * TRI * 16384;

  for (int half = 0; half < 2; ++half){
    const int ti = half ? pr : (31 - pr);
    const int m0 = ti * 128;
    const char* Pt = (const char*)(Spb + (size_t)(ti * (ti + 1) / 2) * 16384);
    const int ksteps = 2 * (ti + 1);

    f32x4 acc[4][4];
    #pragma unroll
    for (int i = 0; i < 4; ++i)
      #pragma unroll
      for (int j = 0; j < 4; ++j) acc[i][j] = (f32x4)0.0f;

    for (int s = 0; s < ksteps; ++s){
      STAGE_AB(Pt + (size_t)(s >> 1) * 32768 + (s & 1) * 128, 256,
               VTb + s * 128, 8192);
      WAITVM0;
      __syncthreads();
      COMPUTE128S();
      __syncthreads();
    }

    const float* lb = lrow + (size_t)b * SEQ + m0;
    float* ob = out + ((size_t)b * SEQ + m0) * DIM + n0;
    #pragma unroll
    for (int i = 0; i < 4; ++i)
      #pragma unroll
      for (int r = 0; r < 4; ++r){
        int row = wr + i*16 + lk*4 + r;
        float inv = 1.0f / lb[row];
        #pragma unroll
        for (int j = 0; j < 4; ++j)
          ob[(size_t)row * DIM + wc + j*16 + lr] = acc[i][j][r] * inv;
      }
  }
}

// ---------------- launch ----------------
extern "C" void kernel_launch(void* const* d_in, const int* in_sizes, int n_in,
                              void* d_out, int out_size, void* d_ws, size_t ws_size,
                              hipStream_t stream)
{
  (void)in_sizes; (void)n_in; (void)out_size; (void)ws_size;
  const float* emb = (const float*)d_in[0];
  const float* Wq  = (const float*)d_in[1];
  const float* Wk  = (const float*)d_in[2];
  const float* Wv  = (const float*)d_in[3];

  char* ws = (char*)d_ws;
  unsigned short* EB = (unsigned short*)ws;                    // 32MB (reused as VT)
  unsigned short* WB = (unsigned short*)(ws + 33554432);       // 6MB: Wq|Wk|Wv bf16
  unsigned short* Qb = (unsigned short*)(ws + 39845888);       // 32MB
  unsigned short* Kb = (unsigned short*)(ws + 73400320);       // 32MB
  unsigned short* Sp = (unsigned short*)(ws + 106954752);      // 66MB packed P tiles
  float*          lr = (float*)(ws + 176160768);               // 64KB row sums
  unsigned short* Vb = (unsigned short*)d_out;                 // V scratch in out buffer
  unsigned short* VT = EB;                                     // alias: E dead after gemm

  hipMemsetAsync(lr, 0, (size_t)NB * SEQ * sizeof(float), stream);

  cvt_kernel<<<16384, 256, 0, stream>>>(emb, EB, 4194304);
  cvt_kernel<<<1024, 256, 0, stream>>>(Wq, WB,           262144);
  cvt_kernel<<<1024, 256, 0, stream>>>(Wk, WB + 1048576, 262144);
  cvt_kernel<<<1024, 256, 0, stream>>>(Wv, WB + 2097152, 262144);

  gemm_qkv<<<768, 512, 0, stream>>>(EB, WB, Qb, Kb, Vb);
  transpose_v<<<dim3(64, 16, 4), 256, 0, stream>>>(Vb, VT);

  sp_gemm<<<dim3(528, NB), 256, 0, stream>>>(Qb, Kb, Sp, lr);
  pv_gemm<<<dim3(128, NB), 256, 0, stream>>>(Sp, VT, lr, (float*)d_out);
}